// Round 1
// baseline (134.703 us; speedup 1.0000x reference)
//
#include <hip/hip_runtime.h>
#include <hip/hip_bf16.h>
#include <cstdint>
#include <cstddef>

// Problem constants
#define B_   4
#define C_   256
#define V_   4096            // 64*64 pixels per batch
#define M_   16384           // B_*V_ query rows
#define N_   2048            // past samples
#define K_   256             // embed dim
#define NC_  4
#define TINV 10.0f           // 1/TEMP
#define EPSN 1e-8f

typedef __bf16 bf16x8 __attribute__((ext_vector_type(8)));
typedef float  f32x4  __attribute__((ext_vector_type(4)));

__device__ __forceinline__ unsigned short f2bf(float f) {
    union { float f; unsigned int u; } v; v.f = f;
    unsigned int u = v.u;
    u += 0x7fffu + ((u >> 16) & 1u);   // RNE
    return (unsigned short)(u >> 16);
}

__device__ __forceinline__ void gl2lds16(const void* g, void* l) {
    __builtin_amdgcn_global_load_lds(
        (__attribute__((address_space(1))) void*)g,
        (__attribute__((address_space(3))) void*)l, 16, 0, 0);
}

// ---------------------------------------------------------------------------
// Kernel 1: normalize past samples (N_ x K_) -> bf16, compute sample class.
// One wave per sample; lane reads float4 (16B), shfl-reduce sumsq.
__global__ __launch_bounds__(256) void prep_past(
        const float* __restrict__ P, const float* __restrict__ L,
        unsigned short* __restrict__ Pn, unsigned char* __restrict__ sClass) {
    int w = threadIdx.x >> 6, l = threadIdx.x & 63;
    int n = blockIdx.x * 4 + w;
    const float4* row = (const float4*)(P + (size_t)n * K_);
    float4 v = row[l];
    float s = v.x*v.x + v.y*v.y + v.z*v.z + v.w*v.w;
    #pragma unroll
    for (int m = 1; m < 64; m <<= 1) s += __shfl_xor(s, m);
    float inv = 1.0f / fmaxf(sqrtf(s), EPSN);
    ushort4 o;
    o.x = f2bf(v.x * inv); o.y = f2bf(v.y * inv);
    o.z = f2bf(v.z * inv); o.w = f2bf(v.w * inv);
    ((ushort4*)(Pn + (size_t)n * K_))[l] = o;
    if (l == 0) {
        const float* lr = L + (size_t)n * NC_;
        int best = 0; float bv = lr[0];
        #pragma unroll
        for (int k = 1; k < NC_; k++) { if (lr[k] > bv) { bv = lr[k]; best = k; } }
        sClass[n] = (unsigned char)best;
    }
}

// ---------------------------------------------------------------------------
// Kernel 2: per-pixel normalize X and transpose (B,C,V) -> row-major (M_,K_)
// bf16. Also pixel class from one-hot y. 64 pixels per block via padded LDS.
__global__ __launch_bounds__(256) void prep_x(
        const float* __restrict__ X, const float* __restrict__ Y,
        unsigned short* __restrict__ Xn, unsigned char* __restrict__ pClass) {
    __shared__ float tile[256][65];   // [c][v], pad 65 -> conflict-free both phases
    __shared__ float sqp[256];
    __shared__ float inv[64];
    int t   = threadIdx.x;
    int b   = blockIdx.x >> 6;
    int v0  = (blockIdx.x & 63) * 64;
    int vi  = t & 63;
    int sub = t >> 6;                  // 0..3
    const float* Xb = X + (size_t)b * C_ * V_ + v0;
    float acc = 0.f;
    #pragma unroll 8
    for (int i = 0; i < 64; i++) {
        int c = i * 4 + sub;
        float val = Xb[(size_t)c * V_ + vi];
        tile[c][vi] = val;
        acc += val * val;
    }
    sqp[t] = acc;
    __syncthreads();
    if (t < 64) {
        float s = sqp[t] + sqp[64 + t] + sqp[128 + t] + sqp[192 + t];
        inv[t] = 1.0f / fmaxf(sqrtf(s), EPSN);
        const float* Yb = Y + (size_t)b * NC_ * V_ + v0 + t;
        int best = 0; float bv = Yb[0];
        #pragma unroll
        for (int k = 1; k < NC_; k++) {
            float yv = Yb[(size_t)k * V_];
            if (yv > bv) { bv = yv; best = k; }
        }
        pClass[(size_t)b * V_ + v0 + t] = (unsigned char)best;
    }
    __syncthreads();
    #pragma unroll 8
    for (int p = 0; p < 64; p++) {
        float val = tile[t][p] * inv[p];
        Xn[(size_t)(b * V_ + v0 + p) * C_ + t] = f2bf(val);
    }
}

// ---------------------------------------------------------------------------
// Kernel 3: fused GEMM (sim = Xn . Pn^T) + exp + class-partitioned per-pixel
// partial sums. 128x128 tile, BK=64, 4 waves in 2x2, 16x16x32 bf16 MFMA.
// Partials: slab = by*2 + colhalf -> 32 slabs, unique writer per (slab,row).
__global__ __launch_bounds__(256) void gemm_loss(
        const unsigned short* __restrict__ A,   // Xn M_ x K_
        const unsigned short* __restrict__ Bm,  // Pn N_ x K_ (B^T layout)
        const unsigned char* __restrict__ pClass,
        const unsigned char* __restrict__ sClass,
        float* __restrict__ pss, float* __restrict__ pso) {
    __shared__ __align__(1024) unsigned short As[128 * 64];
    __shared__ __align__(1024) unsigned short Bs[128 * 64];
    int tid = threadIdx.x;
    int w = tid >> 6, l = tid & 63;
    int m0 = blockIdx.x * 128;
    int n0 = blockIdx.y * 128;
    int wm = (w >> 1) * 64, wn = (w & 1) * 64;
    int q = l >> 4, c0 = l & 15;
    int lrow = l >> 3;            // staging: row within 1KB chunk
    int lcol = (l & 7) * 8;       // staging: col (bf16 elems)

    f32x4 acc[4][4];
    #pragma unroll
    for (int i = 0; i < 4; i++)
        #pragma unroll
        for (int j = 0; j < 4; j++)
            acc[i][j] = (f32x4){0.f, 0.f, 0.f, 0.f};

    for (int k0 = 0; k0 < K_; k0 += 64) {
        #pragma unroll
        for (int i = 0; i < 4; i++) {
            int c = i * 4 + w;    // chunk id 0..15, wave-uniform
            gl2lds16(A  + (size_t)(m0 + c * 8 + lrow) * K_ + k0 + lcol, As + c * 512);
            gl2lds16(Bm + (size_t)(n0 + c * 8 + lrow) * K_ + k0 + lcol, Bs + c * 512);
        }
        __syncthreads();
        #pragma unroll
        for (int kk = 0; kk < 64; kk += 32) {
            bf16x8 af[4], bfv[4];
            #pragma unroll
            for (int mi = 0; mi < 4; mi++)
                af[mi] = *(const bf16x8*)(As + (wm + mi * 16 + c0) * 64 + kk + q * 8);
            #pragma unroll
            for (int ni = 0; ni < 4; ni++)
                bfv[ni] = *(const bf16x8*)(Bs + (wn + ni * 16 + c0) * 64 + kk + q * 8);
            #pragma unroll
            for (int mi = 0; mi < 4; mi++)
                #pragma unroll
                for (int ni = 0; ni < 4; ni++)
                    acc[mi][ni] = __builtin_amdgcn_mfma_f32_16x16x32_bf16(
                        af[mi], bfv[ni], acc[mi][ni], 0, 0, 0);
        }
        __syncthreads();
    }

    // Epilogue: e = exp(10*(sim-1)); partition by class; reduce the 16-lane
    // column group so lane c0==0 holds the per-row sums for this 64-col half.
    int sc[4];
    #pragma unroll
    for (int ni = 0; ni < 4; ni++) sc[ni] = sClass[n0 + wn + ni * 16 + c0];
    int slab = blockIdx.y * 2 + (w & 1);
    #pragma unroll
    for (int mi = 0; mi < 4; mi++) {
        #pragma unroll
        for (int r = 0; r < 4; r++) {
            int row = m0 + wm + mi * 16 + q * 4 + r;
            int pc = pClass[row];
            float ss = 0.f, so = 0.f;
            #pragma unroll
            for (int ni = 0; ni < 4; ni++) {
                float e = __expf((acc[mi][ni][r] - 1.0f) * TINV);
                if (sc[ni] == pc) ss += e; else so += e;
            }
            #pragma unroll
            for (int m = 1; m < 16; m <<= 1) {
                ss += __shfl_xor(ss, m);
                so += __shfl_xor(so, m);
            }
            if (c0 == 0) {
                pss[(size_t)slab * M_ + row] = ss;
                pso[(size_t)slab * M_ + row] = so;
            }
        }
    }
}

// ---------------------------------------------------------------------------
// Kernel 4: per-pixel combine of 32 slabs -> ratio -> per-block sum.
__global__ __launch_bounds__(256) void reduce1(
        const float* __restrict__ pss, const float* __restrict__ pso,
        const unsigned char* __restrict__ pClass,
        const unsigned char* __restrict__ sClass,
        float* __restrict__ bsum) {
    __shared__ int hist[NC_];
    __shared__ float wsum[4];
    int t = threadIdx.x;
    if (t < NC_) hist[t] = 0;
    __syncthreads();
    int lc[NC_] = {0, 0, 0, 0};
    #pragma unroll
    for (int i = 0; i < 8; i++) lc[sClass[t * 8 + i]]++;
    #pragma unroll
    for (int k = 0; k < NC_; k++) if (lc[k]) atomicAdd(&hist[k], lc[k]);
    __syncthreads();
    int p = blockIdx.x * 256 + t;
    float ss = 0.f, so = 0.f;
    #pragma unroll
    for (int s = 0; s < 32; s++) {
        ss += pss[(size_t)s * M_ + p];
        so += pso[(size_t)s * M_ + p];
    }
    int cnt = hist[pClass[p]];
    float ratio = (ss + (float)(N_ - cnt)) / (so + (float)cnt);
    #pragma unroll
    for (int m = 1; m < 64; m <<= 1) ratio += __shfl_xor(ratio, m);
    if ((t & 63) == 0) wsum[t >> 6] = ratio;
    __syncthreads();
    if (t == 0) bsum[blockIdx.x] = wsum[0] + wsum[1] + wsum[2] + wsum[3];
}

// Kernel 5: final 64-value sum -> mean scalar (fully overwrites d_out).
__global__ void reduce2(const float* __restrict__ bsum, float* __restrict__ out) {
    int t = threadIdx.x;
    float v = bsum[t];
    #pragma unroll
    for (int m = 1; m < 64; m <<= 1) v += __shfl_xor(v, m);
    if (t == 0) out[0] = v * (1.0f / (float)M_);
}

// ---------------------------------------------------------------------------
extern "C" void kernel_launch(void* const* d_in, const int* in_sizes, int n_in,
                              void* d_out, int out_size, void* d_ws, size_t ws_size,
                              hipStream_t stream) {
    const float* X = (const float*)d_in[0];   // (B, C, H, W)
    const float* Y = (const float*)d_in[1];   // (B, NC, H, W)
    const float* P = (const float*)d_in[2];   // (N, C)
    const float* L = (const float*)d_in[3];   // (N, NC)

    char* ws = (char*)d_ws;
    unsigned short* Xn    = (unsigned short*)(ws);              // 8 MB  bf16 M_ x K_
    unsigned short* Pn    = (unsigned short*)(ws + 8388608);    // 1 MB  bf16 N_ x K_
    float*          pss   = (float*)(ws + 9437184);             // 2 MB  [32][M_]
    float*          pso   = (float*)(ws + 11534336);            // 2 MB  [32][M_]
    unsigned char*  pCls  = (unsigned char*)(ws + 13631488);    // 16 KB
    unsigned char*  sCls  = (unsigned char*)(ws + 13647872);    // 2 KB
    float*          bsum  = (float*)(ws + 13649920);            // 256 B

    prep_past<<<N_ / 4, 256, 0, stream>>>(P, L, Pn, sCls);
    prep_x<<<B_ * (V_ / 64), 256, 0, stream>>>(X, Y, Xn, pCls);
    dim3 grid(M_ / 128, N_ / 128);
    gemm_loss<<<grid, 256, 0, stream>>>(Xn, Pn, pCls, sCls, pss, pso);
    reduce1<<<M_ / 256, 256, 0, stream>>>(pss, pso, pCls, sCls, bsum);
    reduce2<<<1, 64, 0, stream>>>(bsum, (float*)d_out);
}

// Round 2
// 116.415 us; speedup vs baseline: 1.1571x; 1.1571x over previous
//
#include <hip/hip_runtime.h>
#include <hip/hip_bf16.h>
#include <cstdint>
#include <cstddef>

// Problem constants
#define B_   4
#define C_   256
#define V_   4096            // 64*64 pixels per batch
#define M_   16384           // B_*V_ query rows
#define N_   2048            // past samples
#define K_   256             // embed dim
#define NC_  4
#define TINV 10.0f           // 1/TEMP
#define EPSN 1e-8f

typedef __bf16 bf16x8 __attribute__((ext_vector_type(8)));
typedef float  f32x4  __attribute__((ext_vector_type(4)));

__device__ __forceinline__ unsigned short f2bf(float f) {
    union { float f; unsigned int u; } v; v.f = f;
    unsigned int u = v.u;
    u += 0x7fffu + ((u >> 16) & 1u);   // RNE
    return (unsigned short)(u >> 16);
}

__device__ __forceinline__ void gl2lds16(const void* g, void* l) {
    __builtin_amdgcn_global_load_lds(
        (__attribute__((address_space(1))) void*)g,
        (__attribute__((address_space(3))) void*)l, 16, 0, 0);
}

// ---------------------------------------------------------------------------
// Kernel 1: normalize past samples (N_ x K_) -> bf16, compute sample class.
__global__ __launch_bounds__(256) void prep_past(
        const float* __restrict__ P, const float* __restrict__ L,
        unsigned short* __restrict__ Pn, unsigned char* __restrict__ sClass) {
    int w = threadIdx.x >> 6, l = threadIdx.x & 63;
    int n = blockIdx.x * 4 + w;
    const float4* row = (const float4*)(P + (size_t)n * K_);
    float4 v = row[l];
    float s = v.x*v.x + v.y*v.y + v.z*v.z + v.w*v.w;
    #pragma unroll
    for (int m = 1; m < 64; m <<= 1) s += __shfl_xor(s, m);
    float inv = 1.0f / fmaxf(sqrtf(s), EPSN);
    ushort4 o;
    o.x = f2bf(v.x * inv); o.y = f2bf(v.y * inv);
    o.z = f2bf(v.z * inv); o.w = f2bf(v.w * inv);
    ((ushort4*)(Pn + (size_t)n * K_))[l] = o;
    if (l == 0) {
        const float* lr = L + (size_t)n * NC_;
        int best = 0; float bv = lr[0];
        #pragma unroll
        for (int k = 1; k < NC_; k++) { if (lr[k] > bv) { bv = lr[k]; best = k; } }
        sClass[n] = (unsigned char)best;
    }
}

// ---------------------------------------------------------------------------
// Kernel 2: per-pixel normalize X and transpose (B,C,V) -> row-major (M_,K_)
// bf16. Also pixel class from one-hot y. 64 pixels per block via padded LDS.
__global__ __launch_bounds__(256) void prep_x(
        const float* __restrict__ X, const float* __restrict__ Y,
        unsigned short* __restrict__ Xn, unsigned char* __restrict__ pClass) {
    __shared__ float tile[256][65];   // [c][v], pad 65 -> conflict-free both phases
    __shared__ float sqp[256];
    __shared__ float inv[64];
    int t   = threadIdx.x;
    int b   = blockIdx.x >> 6;
    int v0  = (blockIdx.x & 63) * 64;
    int vi  = t & 63;
    int sub = t >> 6;                  // 0..3
    const float* Xb = X + (size_t)b * C_ * V_ + v0;
    float acc = 0.f;
    #pragma unroll 8
    for (int i = 0; i < 64; i++) {
        int c = i * 4 + sub;
        float val = Xb[(size_t)c * V_ + vi];
        tile[c][vi] = val;
        acc += val * val;
    }
    sqp[t] = acc;
    __syncthreads();
    if (t < 64) {
        float s = sqp[t] + sqp[64 + t] + sqp[128 + t] + sqp[192 + t];
        inv[t] = 1.0f / fmaxf(sqrtf(s), EPSN);
        const float* Yb = Y + (size_t)b * NC_ * V_ + v0 + t;
        int best = 0; float bv = Yb[0];
        #pragma unroll
        for (int k = 1; k < NC_; k++) {
            float yv = Yb[(size_t)k * V_];
            if (yv > bv) { bv = yv; best = k; }
        }
        pClass[(size_t)b * V_ + v0 + t] = (unsigned char)best;
    }
    __syncthreads();
    #pragma unroll 8
    for (int p = 0; p < 64; p++) {
        float val = tile[t][p] * inv[p];
        Xn[(size_t)(b * V_ + v0 + p) * C_ + t] = f2bf(val);
    }
}

// ---------------------------------------------------------------------------
// Kernel 3: fused GEMM (sim = Xn . Pn^T) + exp + class-partitioned per-pixel
// partial sums. 128x128 tile, BK=64, 4 waves in 2x2, 16x16x32 bf16 MFMA.
// LDS layout XOR-swizzled: physical 16B chunk j_p holds logical chunk
// j_p ^ (row & 7)  -> fragment reads spread over all 32 banks (2-way = free),
// instead of 16-way conflicts with the naive 128B row stride.
__global__ __launch_bounds__(256) void gemm_loss(
        const unsigned short* __restrict__ A,   // Xn M_ x K_
        const unsigned short* __restrict__ Bm,  // Pn N_ x K_ (B^T layout)
        const unsigned char* __restrict__ pClass,
        const unsigned char* __restrict__ sClass,
        float* __restrict__ pss, float* __restrict__ pso) {
    __shared__ __align__(1024) unsigned short As[128 * 64];
    __shared__ __align__(1024) unsigned short Bs[128 * 64];
    int tid = threadIdx.x;
    int w = tid >> 6, l = tid & 63;
    int m0 = blockIdx.x * 128;
    int n0 = blockIdx.y * 128;
    int wm = (w >> 1) * 64, wn = (w & 1) * 64;
    int q = l >> 4, c0 = l & 15;
    int lrow   = l >> 3;                       // staging: row within 8-row chunk
    int lcolsw = ((l & 7) ^ lrow) * 8;         // swizzled logical col chunk

    f32x4 acc[4][4];
    #pragma unroll
    for (int i = 0; i < 4; i++)
        #pragma unroll
        for (int j = 0; j < 4; j++)
            acc[i][j] = (f32x4){0.f, 0.f, 0.f, 0.f};

    for (int k0 = 0; k0 < K_; k0 += 64) {
        #pragma unroll
        for (int i = 0; i < 4; i++) {
            int c = i * 4 + w;    // chunk id 0..15, wave-uniform
            gl2lds16(A  + (size_t)(m0 + c * 8 + lrow) * K_ + k0 + lcolsw, As + c * 512);
            gl2lds16(Bm + (size_t)(n0 + c * 8 + lrow) * K_ + k0 + lcolsw, Bs + c * 512);
        }
        __syncthreads();
        #pragma unroll
        for (int kk = 0; kk < 64; kk += 32) {
            bf16x8 af[4], bfv[4];
            #pragma unroll
            for (int mi = 0; mi < 4; mi++) {
                int row = wm + mi * 16 + c0;
                int phys = ((kk >> 3) + q) ^ (c0 & 7);
                af[mi] = *(const bf16x8*)(As + row * 64 + phys * 8);
            }
            #pragma unroll
            for (int ni = 0; ni < 4; ni++) {
                int row = wn + ni * 16 + c0;
                int phys = ((kk >> 3) + q) ^ (c0 & 7);
                bfv[ni] = *(const bf16x8*)(Bs + row * 64 + phys * 8);
            }
            #pragma unroll
            for (int mi = 0; mi < 4; mi++)
                #pragma unroll
                for (int ni = 0; ni < 4; ni++)
                    acc[mi][ni] = __builtin_amdgcn_mfma_f32_16x16x32_bf16(
                        af[mi], bfv[ni], acc[mi][ni], 0, 0, 0);
        }
        __syncthreads();
    }

    // Epilogue: e = exp(10*(sim-1)); partition by class; reduce the 16-lane
    // column group so lane c0==0 holds the per-row sums for this 64-col half.
    int sc[4];
    #pragma unroll
    for (int ni = 0; ni < 4; ni++) sc[ni] = sClass[n0 + wn + ni * 16 + c0];
    int slab = blockIdx.y * 2 + (w & 1);
    #pragma unroll
    for (int mi = 0; mi < 4; mi++) {
        #pragma unroll
        for (int r = 0; r < 4; r++) {
            int row = m0 + wm + mi * 16 + q * 4 + r;
            int pc = pClass[row];
            float ss = 0.f, so = 0.f;
            #pragma unroll
            for (int ni = 0; ni < 4; ni++) {
                float e = __expf((acc[mi][ni][r] - 1.0f) * TINV);
                if (sc[ni] == pc) ss += e; else so += e;
            }
            #pragma unroll
            for (int m = 1; m < 16; m <<= 1) {
                ss += __shfl_xor(ss, m);
                so += __shfl_xor(so, m);
            }
            if (c0 == 0) {
                pss[(size_t)slab * M_ + row] = ss;
                pso[(size_t)slab * M_ + row] = so;
            }
        }
    }
}

// ---------------------------------------------------------------------------
// Kernel 4: per-pixel combine of 32 slabs -> ratio -> per-block sum.
// 256 blocks x 256 threads: 64 pixels/block, 4 slab-groups of 8 in parallel.
__global__ __launch_bounds__(256) void reduce1(
        const float* __restrict__ pss, const float* __restrict__ pso,
        const unsigned char* __restrict__ pClass,
        const unsigned char* __restrict__ sClass,
        float* __restrict__ bsum) {
    __shared__ int hist[NC_];
    __shared__ float lss[4][64], lso[4][64];
    int t = threadIdx.x;
    if (t < NC_) hist[t] = 0;
    __syncthreads();
    int lc[NC_] = {0, 0, 0, 0};
    #pragma unroll
    for (int i = 0; i < 8; i++) lc[sClass[t * 8 + i]]++;
    #pragma unroll
    for (int k = 0; k < NC_; k++) if (lc[k]) atomicAdd(&hist[k], lc[k]);
    int p = blockIdx.x * 64 + (t & 63);
    int g = t >> 6;
    float ss = 0.f, so = 0.f;
    #pragma unroll
    for (int i = 0; i < 8; i++) {
        int s = g * 8 + i;
        ss += pss[(size_t)s * M_ + p];
        so += pso[(size_t)s * M_ + p];
    }
    lss[g][t & 63] = ss;
    lso[g][t & 63] = so;
    __syncthreads();
    if (t < 64) {
        float S = lss[0][t] + lss[1][t] + lss[2][t] + lss[3][t];
        float O = lso[0][t] + lso[1][t] + lso[2][t] + lso[3][t];
        int cnt = hist[pClass[blockIdx.x * 64 + t]];
        float ratio = (S + (float)(N_ - cnt)) / (O + (float)cnt);
        #pragma unroll
        for (int m = 1; m < 64; m <<= 1) ratio += __shfl_xor(ratio, m);
        if (t == 0) bsum[blockIdx.x] = ratio;
    }
}

// Kernel 5: final 256-value sum -> mean scalar (fully overwrites d_out).
__global__ __launch_bounds__(256) void reduce2(
        const float* __restrict__ bsum, float* __restrict__ out) {
    __shared__ float wsum[4];
    int t = threadIdx.x;
    float v = bsum[t];
    #pragma unroll
    for (int m = 1; m < 64; m <<= 1) v += __shfl_xor(v, m);
    if ((t & 63) == 0) wsum[t >> 6] = v;
    __syncthreads();
    if (t == 0) out[0] = (wsum[0] + wsum[1] + wsum[2] + wsum[3]) * (1.0f / (float)M_);
}

// ---------------------------------------------------------------------------
extern "C" void kernel_launch(void* const* d_in, const int* in_sizes, int n_in,
                              void* d_out, int out_size, void* d_ws, size_t ws_size,
                              hipStream_t stream) {
    const float* X = (const float*)d_in[0];   // (B, C, H, W)
    const float* Y = (const float*)d_in[1];   // (B, NC, H, W)
    const float* P = (const float*)d_in[2];   // (N, C)
    const float* L = (const float*)d_in[3];   // (N, NC)

    char* ws = (char*)d_ws;
    unsigned short* Xn    = (unsigned short*)(ws);              // 8 MB  bf16 M_ x K_
    unsigned short* Pn    = (unsigned short*)(ws + 8388608);    // 1 MB  bf16 N_ x K_
    float*          pss   = (float*)(ws + 9437184);             // 2 MB  [32][M_]
    float*          pso   = (float*)(ws + 11534336);            // 2 MB  [32][M_]
    unsigned char*  pCls  = (unsigned char*)(ws + 13631488);    // 16 KB
    unsigned char*  sCls  = (unsigned char*)(ws + 13647872);    // 2 KB
    float*          bsum  = (float*)(ws + 13649920);            // 1 KB

    prep_past<<<N_ / 4, 256, 0, stream>>>(P, L, Pn, sCls);
    prep_x<<<B_ * (V_ / 64), 256, 0, stream>>>(X, Y, Xn, pCls);
    dim3 grid(M_ / 128, N_ / 128);
    gemm_loss<<<grid, 256, 0, stream>>>(Xn, Pn, pCls, sCls, pss, pso);
    reduce1<<<M_ / 64, 256, 0, stream>>>(pss, pso, pCls, sCls, bsum);
    reduce2<<<1, 256, 0, stream>>>(bsum, (float*)d_out);
}